// Round 12
// baseline (786.907 us; speedup 1.0000x reference)
//
#include <hip/hip_runtime.h>

#define N_NODES 100000
#define N_EDGES 3200000
#define NB 782          // dst buckets of 128 nodes: ceil(100000/128)
#define BCAP 5120       // max edges per bucket (avg 4096, 16 sigma guard)
#define CHUNK_EDGES 16384
#define NCHUNKS ((N_EDGES + CHUNK_EDGES - 1) / CHUNK_EDGES)  // 196

typedef unsigned int uint;
typedef __attribute__((ext_vector_type(2))) uint u2v;
typedef __attribute__((ext_vector_type(4))) uint u4v;
typedef __attribute__((ext_vector_type(2))) float f2v;
typedef __attribute__((ext_vector_type(8))) short s8v;   // 8 bf16 (4 VGPRs)
typedef __attribute__((ext_vector_type(4))) float f32x4; // mfma acc

// ---------- CSR build: deterministic two-pass bucket partition (proven) ----------

__global__ void detect_fmt(const uint* __restrict__ e, int* __restrict__ flag,
                           int* __restrict__ row_ptr) {
    if (threadIdx.x == 0) {
        *flag = (e[1] == 0u && e[3] == 0u && e[5] == 0u && e[7] == 0u) ? 1 : 0;
        row_ptr[N_NODES] = N_EDGES;
    }
}

__device__ __forceinline__ int load_idx(const void* edges, int fmt, long long i) {
    return fmt ? (int)((const long long*)edges)[i] : ((const int*)edges)[i];
}

__global__ __launch_bounds__(256) void part_hist(const void* __restrict__ edges,
                                                 const int* __restrict__ flag,
                                                 int* __restrict__ hist2,
                                                 int* __restrict__ bcount) {
    __shared__ int cnt[NB];
    for (int i = threadIdx.x; i < NB; i += 256) cnt[i] = 0;
    __syncthreads();
    int fmt = *flag;
    int c = blockIdx.x;
    int beg = c * CHUNK_EDGES, end = min(beg + CHUNK_EDGES, N_EDGES);
    for (int i = beg + threadIdx.x; i < end; i += 256) {
        int dst = load_idx(edges, fmt, (long long)N_EDGES + i);
        atomicAdd(&cnt[dst >> 7], 1);
    }
    __syncthreads();
    for (int i = threadIdx.x; i < NB; i += 256) {
        hist2[c * NB + i] = cnt[i];
        if (cnt[i]) atomicAdd(&bcount[i], cnt[i]);
    }
}

__global__ void scan_kernel(const int* __restrict__ count, int* __restrict__ off_out, int n) {
    __shared__ int sums[1024];
    int t = threadIdx.x;
    int chunk = (n + 1023) >> 10;
    int beg = t * chunk;
    int end = min(beg + chunk, n);
    int s = 0;
    for (int i = beg; i < end; ++i) s += count[i];
    sums[t] = s;
    __syncthreads();
    int val = s;
    for (int off = 1; off < 1024; off <<= 1) {
        int other = (t >= off) ? sums[t - off] : 0;
        __syncthreads();
        val += other;
        sums[t] = val;
        __syncthreads();
    }
    int run = val - s;
    for (int i = beg; i < end; ++i) {
        off_out[i] = run;
        run += count[i];
    }
    if (end >= n) off_out[n] = run;
}

__global__ __launch_bounds__(256) void chunk_scan(const int* __restrict__ hist2,
                                                  const int* __restrict__ boff,
                                                  int* __restrict__ base2) {
    __shared__ int s[256];
    int b = blockIdx.x;
    int t = threadIdx.x;
    int v = (t < NCHUNKS) ? hist2[t * NB + b] : 0;
    s[t] = v;
    __syncthreads();
    int val = v;
    for (int off = 1; off < 256; off <<= 1) {
        int o = (t >= off) ? s[t - off] : 0;
        __syncthreads();
        val += o;
        s[t] = val;
        __syncthreads();
    }
    if (t < NCHUNKS) base2[t * NB + b] = boff[b] + val - v;
}

__global__ __launch_bounds__(256) void part_scatter(const void* __restrict__ edges,
                                                    const int* __restrict__ flag,
                                                    const int* __restrict__ base2,
                                                    uint* __restrict__ tmp) {
    __shared__ int cur[NB];
    int c = blockIdx.x;
    for (int i = threadIdx.x; i < NB; i += 256) cur[i] = base2[c * NB + i];
    __syncthreads();
    int fmt = *flag;
    int beg = c * CHUNK_EDGES, end = min(beg + CHUNK_EDGES, N_EDGES);
    for (int i = beg + threadIdx.x; i < end; i += 256) {
        int src = load_idx(edges, fmt, i);
        int dst = load_idx(edges, fmt, (long long)N_EDGES + i);
        int b = dst >> 7;
        int pos = atomicAdd(&cur[b], 1);
        tmp[pos] = ((uint)(dst & 127) << 17) | (uint)src;  // src < 2^17
    }
}

__global__ __launch_bounds__(256) void bucket_finalize(const uint* __restrict__ tmp,
                                                       const int* __restrict__ boff,
                                                       int* __restrict__ row_ptr,
                                                       int* __restrict__ esorted) {
    __shared__ uint s1[BCAP];
    __shared__ int s2[BCAP];
    __shared__ int cnt[128], pref[128], cur[128];
    int b = blockIdx.x;
    int beg = boff[b];
    int n = boff[b + 1] - beg;
    if (n > BCAP) n = BCAP;
    int t = threadIdx.x;
    if (t < 128) cnt[t] = 0;
    __syncthreads();
    for (int e = t; e < n; e += 256) {
        uint k = tmp[beg + e];
        s1[e] = k;
        atomicAdd(&cnt[k >> 17], 1);
    }
    __syncthreads();
    if (t < 128) pref[t] = cnt[t];
    __syncthreads();
    for (int off = 1; off < 128; off <<= 1) {
        int v = (t < 128 && t >= off) ? pref[t - off] : 0;
        __syncthreads();
        if (t < 128) pref[t] += v;
        __syncthreads();
    }
    if (t < 128) {
        int ex = pref[t] - cnt[t];
        cur[t] = ex;
        int node = b * 128 + t;
        if (node < N_NODES) row_ptr[node] = beg + ex;
    }
    __syncthreads();
    for (int e = t; e < n; e += 256) {
        uint k = s1[e];
        int p = atomicAdd(&cur[k >> 17], 1);
        s2[p] = (int)(k & 0x1FFFF);
    }
    __syncthreads();
    for (int e = t; e < n; e += 256) esorted[beg + e] = s2[e];
}

// ---------- bf16 helpers ----------

__device__ __forceinline__ uint bf16pack(float a, float b) {
    uint ua = __float_as_uint(a);
    ua = (ua + 0x7FFFu + ((ua >> 16) & 1u)) >> 16;  // RNE
    uint ub = __float_as_uint(b);
    ub = (ub + 0x7FFFu + ((ub >> 16) & 1u)) >> 16;
    return ua | (ub << 16);
}
__device__ __forceinline__ float bf_lo(uint u) { return __uint_as_float(u << 16); }
__device__ __forceinline__ float bf_hi(uint u) { return __uint_as_float(u & 0xFFFF0000u); }

// ---------- linear collapse: suffix products + bias vectors ----------
// The network is fully linear (no activation):
//   out = (I+A)^5 h S0 + sum_l (I+A)^{4-l} 1 (b_l^T S_{l+1}),  S_l = W_l...W_4.
// suffix_chain (1 block): S0 (128x64 fp32) and c_l = b_l^T S_{l+1} (c_all[l][64]).

__global__ __launch_bounds__(256) void suffix_chain(
    const float* __restrict__ W0, const float* __restrict__ W1,
    const float* __restrict__ W2, const float* __restrict__ W3,
    const float* __restrict__ W4,
    const float* __restrict__ b0, const float* __restrict__ b1,
    const float* __restrict__ b2, const float* __restrict__ b3,
    const float* __restrict__ b4,
    float* __restrict__ S0g, float* __restrict__ c_all) {
    __shared__ float Sa[128 * 64], Sb[128 * 64];
    int t = threadIdx.x;
    for (int i = t; i < 128 * 64; i += 256) Sa[i] = W4[i];  // S4
    if (t < 64) c_all[4 * 64 + t] = b4[t];                  // c4
    __syncthreads();
    if (t < 64) {  // c3 = b3^T S4
        float s = 0.f;
        for (int k = 0; k < 128; ++k) s += b3[k] * Sa[k * 64 + t];
        c_all[3 * 64 + t] = s;
    }
    for (int i = t; i < 128 * 64; i += 256) {  // S3 = W3 @ S4
        int r = i >> 6, c = i & 63;
        float s = 0.f;
        for (int k = 0; k < 128; ++k) s += W3[r * 128 + k] * Sa[k * 64 + c];
        Sb[i] = s;
    }
    __syncthreads();
    if (t < 64) {  // c2 = b2^T S3
        float s = 0.f;
        for (int k = 0; k < 128; ++k) s += b2[k] * Sb[k * 64 + t];
        c_all[2 * 64 + t] = s;
    }
    for (int i = t; i < 128 * 64; i += 256) {  // S2 = W2 @ S3
        int r = i >> 6, c = i & 63;
        float s = 0.f;
        for (int k = 0; k < 128; ++k) s += W2[r * 128 + k] * Sb[k * 64 + c];
        Sa[i] = s;
    }
    __syncthreads();
    if (t < 64) {  // c1 = b1^T S2
        float s = 0.f;
        for (int k = 0; k < 128; ++k) s += b1[k] * Sa[k * 64 + t];
        c_all[1 * 64 + t] = s;
    }
    for (int i = t; i < 128 * 64; i += 256) {  // S1 = W1 @ S2
        int r = i >> 6, c = i & 63;
        float s = 0.f;
        for (int k = 0; k < 128; ++k) s += W1[r * 128 + k] * Sa[k * 64 + c];
        Sb[i] = s;
    }
    __syncthreads();
    if (t < 64) {  // c0 = b0^T S1
        float s = 0.f;
        for (int k = 0; k < 128; ++k) s += b0[k] * Sb[k * 64 + t];
        c_all[0 * 64 + t] = s;
    }
    for (int i = t; i < 128 * 64; i += 256) {  // S0 = W0 @ S1 -> global
        int r = i >> 6, c = i & 63;
        float s = 0.f;
        for (int k = 0; k < 128; ++k) s += W0[r * 128 + k] * Sb[k * 64 + c];
        S0g[i] = s;
    }
}

// Transpose S0 (fp32 [128][64]) -> bf16 [n][c16] u4v, XOR-swizzled.
__global__ __launch_bounds__(256) void prep_z(const float* __restrict__ S0,
                                              u4v* __restrict__ Wt) {
    int idx = blockIdx.x * 256 + threadIdx.x;  // n*16 + c16, 1024 total
    if (idx >= 64 * 16) return;
    int n = idx >> 4, c16 = idx & 15;
    u4v o;
#pragma unroll
    for (int q = 0; q < 4; ++q)
        o[q] = bf16pack(S0[(size_t)(c16 * 8 + 2 * q) * 64 + n],
                        S0[(size_t)(c16 * 8 + 2 * q + 1) * 64 + n]);
    Wt[n * 16 + (c16 ^ (n & 7))] = o;
}

// ---------- degree polynomial (exact fp32, integer-valued) ----------

__global__ void deg_init(const int* __restrict__ row_ptr, float* __restrict__ d1) {
    int v = blockIdx.x * 256 + threadIdx.x;
    if (v < N_NODES) d1[v] = (float)(row_ptr[v + 1] - row_ptr[v]) + 1.0f;
}

// dn[v] = d[v] + sum_{u in in(v)} d[u]   (d is 400KB -> L2-resident gathers)
__global__ __launch_bounds__(256) void agg_scalar(const float* __restrict__ d,
                                                  const int* __restrict__ row_ptr,
                                                  const int* __restrict__ esrc,
                                                  float* __restrict__ dn) {
    int v = blockIdx.x * 256 + threadIdx.x;
    if (v >= N_NODES) return;
    int beg = row_ptr[v], end = row_ptr[v + 1];
    float s = d[v];
    for (int i = beg; i < end; ++i) s += d[esrc[i]];
    dn[v] = s;
}

// ---------- 64-dim aggregation passes (streaming, 2 edges/wave-instr) ----------
// zn[v] = z[v] + sum_{u in in(v)} z[u]   (bf16 -> bf16)

__global__ __launch_bounds__(256) void agg64_step(const uint* __restrict__ z,
                                                  const int* __restrict__ row_ptr,
                                                  const int* __restrict__ esrc,
                                                  uint* __restrict__ zn) {
    int lane = threadIdx.x & 63;
    int l32 = lane & 31;
    int half = lane >> 5;
    int wid = (blockIdx.x * blockDim.x + threadIdx.x) >> 6;
    int nw = (gridDim.x * blockDim.x) >> 6;
    for (int v = wid; v < N_NODES; v += nw) {
        f2v a = {0.f, 0.f};
        int beg = row_ptr[v], end = row_ptr[v + 1];
        int i = beg;
        for (; i + 16 <= end; i += 16) {
            uint k[8], u[8];
#pragma unroll
            for (int j = 0; j < 8; ++j) k[j] = (uint)esrc[i + 2 * j + half];
#pragma unroll
            for (int j = 0; j < 8; ++j) u[j] = z[k[j] * 32u + (uint)l32];
#pragma unroll
            for (int j = 0; j < 8; ++j) {
                f2v t = {bf_lo(u[j]), bf_hi(u[j])};
                a += t;
            }
        }
        for (; i < end; i += 2) {
            int idx = i + half;
            uint uu = 0u;
            if (idx < end) uu = z[(uint)esrc[idx] * 32u + (uint)l32];
            f2v t = {bf_lo(uu), bf_hi(uu)};
            a += t;
        }
        a.x += __shfl_xor(a.x, 32);
        a.y += __shfl_xor(a.y, 32);
        if (half == 0) {
            uint self = z[(uint)v * 32u + (uint)l32];
            __builtin_nontemporal_store(bf16pack(a.x + bf_lo(self), a.y + bf_hi(self)),
                                        &zn[(uint)v * 32u + (uint)l32]);
        }
    }
}

// Final pass: out[v] = z4[v] + sum_u z4[u]
//                    + d4[v]*c0 + d3[v]*c1 + d2[v]*c2 + (deg+1)*c3 + c4   (fp32)
__global__ __launch_bounds__(256) void agg64_last(const uint* __restrict__ z,
                                                  const int* __restrict__ row_ptr,
                                                  const int* __restrict__ esrc,
                                                  const float* __restrict__ d2,
                                                  const float* __restrict__ d3,
                                                  const float* __restrict__ d4,
                                                  const float* __restrict__ c_all,
                                                  float* __restrict__ out) {
    int lane = threadIdx.x & 63;
    int l32 = lane & 31;
    int half = lane >> 5;
    int wid = (blockIdx.x * blockDim.x + threadIdx.x) >> 6;
    int nw = (gridDim.x * blockDim.x) >> 6;
    f2v c0v = ((const f2v*)(c_all + 0))[l32];
    f2v c1v = ((const f2v*)(c_all + 64))[l32];
    f2v c2v = ((const f2v*)(c_all + 128))[l32];
    f2v c3v = ((const f2v*)(c_all + 192))[l32];
    f2v c4v = ((const f2v*)(c_all + 256))[l32];
    for (int v = wid; v < N_NODES; v += nw) {
        f2v a = {0.f, 0.f};
        int beg = row_ptr[v], end = row_ptr[v + 1];
        int i = beg;
        for (; i + 16 <= end; i += 16) {
            uint k[8], u[8];
#pragma unroll
            for (int j = 0; j < 8; ++j) k[j] = (uint)esrc[i + 2 * j + half];
#pragma unroll
            for (int j = 0; j < 8; ++j) u[j] = z[k[j] * 32u + (uint)l32];
#pragma unroll
            for (int j = 0; j < 8; ++j) {
                f2v t = {bf_lo(u[j]), bf_hi(u[j])};
                a += t;
            }
        }
        for (; i < end; i += 2) {
            int idx = i + half;
            uint uu = 0u;
            if (idx < end) uu = z[(uint)esrc[idx] * 32u + (uint)l32];
            f2v t = {bf_lo(uu), bf_hi(uu)};
            a += t;
        }
        a.x += __shfl_xor(a.x, 32);
        a.y += __shfl_xor(a.y, 32);
        if (half == 0) {
            uint self = z[(uint)v * 32u + (uint)l32];
            float w4 = d4[v], w3 = d3[v], w2 = d2[v];
            float w1 = (float)(end - beg) + 1.0f;
            f2v o;
            o.x = a.x + bf_lo(self) + w4 * c0v.x + w3 * c1v.x + w2 * c2v.x + w1 * c3v.x + c4v.x;
            o.y = a.y + bf_hi(self) + w4 * c0v.y + w3 * c1v.y + w2 * c2v.y + w1 * c3v.y + c4v.y;
            __builtin_nontemporal_store(o, &((f2v*)out)[(uint)v * 32u + (uint)l32]);
        }
    }
}

// ---------- MFMA GEMM: z0 = h (fp32 [N][128]) @ S0 -> bf16 [N][64] ----------

template <int NOUT, bool A_BF16>
__global__ __launch_bounds__(256) void mfma_gemm(const void* __restrict__ xv,
                                                 const u4v* __restrict__ Wt,
                                                 uint* __restrict__ y) {
    constexpr int STAGE = 32768 + NOUT * 256;
    constexpr int EPIL = 128 * NOUT * 4;
    constexpr int SMEM = STAGE > EPIL ? STAGE : EPIL;
    __shared__ char raw[SMEM];
    u4v* Asm = (u4v*)raw;                  // [128][16] swizzled
    u4v* Bsm = (u4v*)(raw + 32768);        // [NOUT][16] swizzled
    float* Cst = (float*)raw;              // [128][NOUT] epilogue overlay
    int tid = threadIdx.x;
    int m0 = blockIdx.x * 128;

    if constexpr (A_BF16) {
        const u4v* xp = (const u4v*)xv;
#pragma unroll
        for (int i = 0; i < 8; ++i) {
            int idx = tid + i * 256;
            int r = idx >> 4, c16 = idx & 15;
            int m = m0 + r;
            if (m >= N_NODES) m = N_NODES - 1;
            Asm[r * 16 + (c16 ^ (r & 7))] = xp[(size_t)m * 16 + c16];
        }
    } else {
        const float* x = (const float*)xv;
#pragma unroll
        for (int i = 0; i < 8; ++i) {
            int idx = tid + i * 256;
            int r = idx >> 4, c16 = idx & 15;
            int m = m0 + r;
            if (m >= N_NODES) m = N_NODES - 1;
            const float* src = &x[(size_t)m * 128 + c16 * 8];
            float4 v0 = *(const float4*)src;
            float4 v1 = *(const float4*)(src + 4);
            u4v o = {bf16pack(v0.x, v0.y), bf16pack(v0.z, v0.w),
                     bf16pack(v1.x, v1.y), bf16pack(v1.z, v1.w)};
            Asm[r * 16 + (c16 ^ (r & 7))] = o;
        }
    }
#pragma unroll
    for (int i = 0; i < NOUT * 16 / 256; ++i) Bsm[tid + i * 256] = Wt[tid + i * 256];
    __syncthreads();

    constexpr int NF = NOUT / 64;
    int lane = tid & 63;
    int w = tid >> 6;
    int n0w = w * (NOUT / 4);
    int lhi = lane >> 4, llo = lane & 15;
    f32x4 acc[8][NF];
#pragma unroll
    for (int i = 0; i < 8; ++i)
#pragma unroll
        for (int j = 0; j < NF; ++j) acc[i][j] = (f32x4){0.f, 0.f, 0.f, 0.f};

#pragma unroll
    for (int ks = 0; ks < 4; ++ks) {
        int cb = ks * 4 + lhi;
        s8v bfr[NF];
#pragma unroll
        for (int j = 0; j < NF; ++j) {
            int col = n0w + j * 16 + llo;
            u4v t = Bsm[col * 16 + (cb ^ (col & 7))];
            bfr[j] = *(s8v*)&t;
        }
#pragma unroll
        for (int i = 0; i < 8; ++i) {
            int row = i * 16 + llo;
            u4v t = Asm[row * 16 + (cb ^ (row & 7))];
            s8v a = *(s8v*)&t;
#pragma unroll
            for (int j = 0; j < NF; ++j)
                acc[i][j] = __builtin_amdgcn_mfma_f32_16x16x32_bf16(a, bfr[j], acc[i][j], 0, 0, 0);
        }
    }
    __syncthreads();
#pragma unroll
    for (int i = 0; i < 8; ++i)
#pragma unroll
        for (int j = 0; j < NF; ++j)
#pragma unroll
            for (int r = 0; r < 4; ++r)
                Cst[(i * 16 + lhi * 4 + r) * NOUT + n0w + j * 16 + llo] = acc[i][j][r];
    __syncthreads();
#pragma unroll
    for (int i = 0; i < 128 * NOUT / 2 / 256; ++i) {
        int idx = tid + i * 256;
        int m = idx / (NOUT / 2), np = idx % (NOUT / 2);
        if (m0 + m < N_NODES)
            y[(size_t)(m0 + m) * (NOUT / 2) + np] =
                bf16pack(Cst[m * NOUT + 2 * np], Cst[m * NOUT + 2 * np + 1]);
    }
}

extern "C" void kernel_launch(void* const* d_in, const int* in_sizes, int n_in,
                              void* d_out, int out_size, void* d_ws, size_t ws_size,
                              hipStream_t stream) {
    const float* h_in = (const float*)d_in[0];
    const void* edges = d_in[1];
    const float* W[5] = {(const float*)d_in[2], (const float*)d_in[4], (const float*)d_in[6],
                         (const float*)d_in[8], (const float*)d_in[10]};
    const float* B[5] = {(const float*)d_in[3], (const float*)d_in[5], (const float*)d_in[7],
                         (const float*)d_in[9], (const float*)d_in[11]};

    size_t off = 0;
    auto alloc = [&](size_t bytes) {
        void* p = (char*)d_ws + off;
        off = (off + bytes + 255) & ~(size_t)255;
        return p;
    };
    int* esorted = (int*)alloc((size_t)N_EDGES * 4);            // 12.8 MB
    int* row_ptr = (int*)alloc((size_t)(N_NODES + 1) * 4);
    int* hist2 = (int*)alloc((size_t)NCHUNKS * NB * 4);
    int* base2 = (int*)alloc((size_t)NCHUNKS * NB * 4);
    int* bcount = (int*)alloc((size_t)NB * 4);
    int* boff = (int*)alloc((size_t)(NB + 1) * 4);
    int* flag = (int*)alloc(256);
    float* S0g = (float*)alloc(128 * 64 * 4);                   // 32 KB
    float* c_all = (float*)alloc(5 * 64 * 4);
    u4v* Wt_z = (u4v*)alloc((size_t)64 * 16 * 16);              // 16 KB
    float* d1 = (float*)alloc((size_t)N_NODES * 4);
    float* d2 = (float*)alloc((size_t)N_NODES * 4);
    float* d3 = (float*)alloc((size_t)N_NODES * 4);
    float* d4 = (float*)alloc((size_t)N_NODES * 4);
    uint* zA = (uint*)alloc((size_t)N_NODES * 32 * 4);          // 12.8 MB
    uint* zB = (uint*)alloc((size_t)N_NODES * 32 * 4);          // 12.8 MB
    uint* tmp = (uint*)alloc((size_t)N_EDGES * 4);              // 12.8 MB (build only)

    // ---- build CSR ----
    detect_fmt<<<1, 64, 0, stream>>>((const uint*)edges, flag, row_ptr);
    hipMemsetAsync(bcount, 0, (size_t)NB * 4, stream);
    part_hist<<<NCHUNKS, 256, 0, stream>>>(edges, flag, hist2, bcount);
    scan_kernel<<<1, 1024, 0, stream>>>(bcount, boff, NB);
    chunk_scan<<<NB, 256, 0, stream>>>(hist2, boff, base2);
    part_scatter<<<NCHUNKS, 256, 0, stream>>>(edges, flag, base2, tmp);
    bucket_finalize<<<NB, 256, 0, stream>>>(tmp, boff, row_ptr, esorted);

    // ---- collapse prep: S0 = W0..W4, c_l = b_l^T S_{l+1}; transpose S0 ----
    suffix_chain<<<1, 256, 0, stream>>>(W[0], W[1], W[2], W[3], W[4],
                                        B[0], B[1], B[2], B[3], B[4], S0g, c_all);
    prep_z<<<4, 256, 0, stream>>>(S0g, Wt_z);

    // ---- degree polynomial d_k = (I+A)^k 1 (exact) ----
    deg_init<<<(N_NODES + 255) / 256, 256, 0, stream>>>(row_ptr, d1);
    agg_scalar<<<(N_NODES + 255) / 256, 256, 0, stream>>>(d1, row_ptr, esorted, d2);
    agg_scalar<<<(N_NODES + 255) / 256, 256, 0, stream>>>(d2, row_ptr, esorted, d3);
    agg_scalar<<<(N_NODES + 255) / 256, 256, 0, stream>>>(d3, row_ptr, esorted, d4);

    // ---- z0 = h @ S0; z_{k+1} = z_k + A z_k (x4); final pass + bias poly ----
    mfma_gemm<64, false><<<(N_NODES + 127) / 128, 256, 0, stream>>>(h_in, Wt_z, zA);
    agg64_step<<<2048, 256, 0, stream>>>(zA, row_ptr, esorted, zB);  // z1
    agg64_step<<<2048, 256, 0, stream>>>(zB, row_ptr, esorted, zA);  // z2
    agg64_step<<<2048, 256, 0, stream>>>(zA, row_ptr, esorted, zB);  // z3
    agg64_step<<<2048, 256, 0, stream>>>(zB, row_ptr, esorted, zA);  // z4
    agg64_last<<<2048, 256, 0, stream>>>(zA, row_ptr, esorted, d2, d3, d4, c_all,
                                         (float*)d_out);
}

// Round 13
// 580.249 us; speedup vs baseline: 1.3562x; 1.3562x over previous
//
#include <hip/hip_runtime.h>

#define N_NODES 100000
#define N_EDGES 3200000
#define NB 782          // dst buckets of 128 nodes: ceil(100000/128)
#define BCAP 5120       // max edges per bucket (avg 4096, 16 sigma guard)
#define CHUNK_EDGES 16384
#define NCHUNKS ((N_EDGES + CHUNK_EDGES - 1) / CHUNK_EDGES)  // 196

typedef unsigned int uint;
typedef __attribute__((ext_vector_type(2))) uint u2v;
typedef __attribute__((ext_vector_type(4))) uint u4v;
typedef __attribute__((ext_vector_type(2))) float f2v;
typedef __attribute__((ext_vector_type(8))) short s8v;   // 8 bf16 (4 VGPRs)
typedef __attribute__((ext_vector_type(4))) float f32x4; // mfma acc

// ---------- CSR build: deterministic two-pass bucket partition (proven) ----------

__global__ void detect_fmt(const uint* __restrict__ e, int* __restrict__ flag,
                           int* __restrict__ row_ptr) {
    if (threadIdx.x == 0) {
        *flag = (e[1] == 0u && e[3] == 0u && e[5] == 0u && e[7] == 0u) ? 1 : 0;
        row_ptr[N_NODES] = N_EDGES;
    }
}

__device__ __forceinline__ int load_idx(const void* edges, int fmt, long long i) {
    return fmt ? (int)((const long long*)edges)[i] : ((const int*)edges)[i];
}

__global__ __launch_bounds__(256) void part_hist(const void* __restrict__ edges,
                                                 const int* __restrict__ flag,
                                                 int* __restrict__ hist2,
                                                 int* __restrict__ bcount) {
    __shared__ int cnt[NB];
    for (int i = threadIdx.x; i < NB; i += 256) cnt[i] = 0;
    __syncthreads();
    int fmt = *flag;
    int c = blockIdx.x;
    int beg = c * CHUNK_EDGES, end = min(beg + CHUNK_EDGES, N_EDGES);
    for (int i = beg + threadIdx.x; i < end; i += 256) {
        int dst = load_idx(edges, fmt, (long long)N_EDGES + i);
        atomicAdd(&cnt[dst >> 7], 1);
    }
    __syncthreads();
    for (int i = threadIdx.x; i < NB; i += 256) {
        hist2[c * NB + i] = cnt[i];
        if (cnt[i]) atomicAdd(&bcount[i], cnt[i]);
    }
}

__global__ void scan_kernel(const int* __restrict__ count, int* __restrict__ off_out, int n) {
    __shared__ int sums[1024];
    int t = threadIdx.x;
    int chunk = (n + 1023) >> 10;
    int beg = t * chunk;
    int end = min(beg + chunk, n);
    int s = 0;
    for (int i = beg; i < end; ++i) s += count[i];
    sums[t] = s;
    __syncthreads();
    int val = s;
    for (int off = 1; off < 1024; off <<= 1) {
        int other = (t >= off) ? sums[t - off] : 0;
        __syncthreads();
        val += other;
        sums[t] = val;
        __syncthreads();
    }
    int run = val - s;
    for (int i = beg; i < end; ++i) {
        off_out[i] = run;
        run += count[i];
    }
    if (end >= n) off_out[n] = run;
}

__global__ __launch_bounds__(256) void chunk_scan(const int* __restrict__ hist2,
                                                  const int* __restrict__ boff,
                                                  int* __restrict__ base2) {
    __shared__ int s[256];
    int b = blockIdx.x;
    int t = threadIdx.x;
    int v = (t < NCHUNKS) ? hist2[t * NB + b] : 0;
    s[t] = v;
    __syncthreads();
    int val = v;
    for (int off = 1; off < 256; off <<= 1) {
        int o = (t >= off) ? s[t - off] : 0;
        __syncthreads();
        val += o;
        s[t] = val;
        __syncthreads();
    }
    if (t < NCHUNKS) base2[t * NB + b] = boff[b] + val - v;
}

__global__ __launch_bounds__(256) void part_scatter(const void* __restrict__ edges,
                                                    const int* __restrict__ flag,
                                                    const int* __restrict__ base2,
                                                    uint* __restrict__ tmp) {
    __shared__ int cur[NB];
    int c = blockIdx.x;
    for (int i = threadIdx.x; i < NB; i += 256) cur[i] = base2[c * NB + i];
    __syncthreads();
    int fmt = *flag;
    int beg = c * CHUNK_EDGES, end = min(beg + CHUNK_EDGES, N_EDGES);
    for (int i = beg + threadIdx.x; i < end; i += 256) {
        int src = load_idx(edges, fmt, i);
        int dst = load_idx(edges, fmt, (long long)N_EDGES + i);
        int b = dst >> 7;
        int pos = atomicAdd(&cur[b], 1);
        tmp[pos] = ((uint)(dst & 127) << 17) | (uint)src;  // src < 2^17
    }
}

__global__ __launch_bounds__(256) void bucket_finalize(const uint* __restrict__ tmp,
                                                       const int* __restrict__ boff,
                                                       int* __restrict__ row_ptr,
                                                       int* __restrict__ esorted) {
    __shared__ uint s1[BCAP];
    __shared__ int s2[BCAP];
    __shared__ int cnt[128], pref[128], cur[128];
    int b = blockIdx.x;
    int beg = boff[b];
    int n = boff[b + 1] - beg;
    if (n > BCAP) n = BCAP;
    int t = threadIdx.x;
    if (t < 128) cnt[t] = 0;
    __syncthreads();
    for (int e = t; e < n; e += 256) {
        uint k = tmp[beg + e];
        s1[e] = k;
        atomicAdd(&cnt[k >> 17], 1);
    }
    __syncthreads();
    if (t < 128) pref[t] = cnt[t];
    __syncthreads();
    for (int off = 1; off < 128; off <<= 1) {
        int v = (t < 128 && t >= off) ? pref[t - off] : 0;
        __syncthreads();
        if (t < 128) pref[t] += v;
        __syncthreads();
    }
    if (t < 128) {
        int ex = pref[t] - cnt[t];
        cur[t] = ex;
        int node = b * 128 + t;
        if (node < N_NODES) row_ptr[node] = beg + ex;
    }
    __syncthreads();
    for (int e = t; e < n; e += 256) {
        uint k = s1[e];
        int p = atomicAdd(&cur[k >> 17], 1);
        s2[p] = (int)(k & 0x1FFFF);
    }
    __syncthreads();
    for (int e = t; e < n; e += 256) esorted[beg + e] = s2[e];
}

// ---------- bf16 helpers ----------

__device__ __forceinline__ uint bf16pack(float a, float b) {
    uint ua = __float_as_uint(a);
    ua = (ua + 0x7FFFu + ((ua >> 16) & 1u)) >> 16;  // RNE
    uint ub = __float_as_uint(b);
    ub = (ub + 0x7FFFu + ((ub >> 16) & 1u)) >> 16;
    return ua | (ub << 16);
}
__device__ __forceinline__ float bf_lo(uint u) { return __uint_as_float(u << 16); }
__device__ __forceinline__ float bf_hi(uint u) { return __uint_as_float(u & 0xFFFF0000u); }

// ---------- linear collapse prep (parallelized) ----------
// out = (I+A)^5 h S0 + sum_l (I+A)^{4-l} 1 c_l,  S_l = W_l...W_4, c_l = b_l^T S_{l+1}.
// One stage per launch: Sout[128][64] = Wl[128][128] @ Sin[128][64]; c = bl^T Sin.
// Blocks 0-31: 4 rows each (thread = 1 output, 128-MAC from LDS; W-row scalar
// loads are wave-broadcast + L2-hot). Block 32: the c vector.

__global__ __launch_bounds__(256) void matstage(const float* __restrict__ Wl,
                                                const float* __restrict__ bl,
                                                const float* __restrict__ Sin,
                                                float* __restrict__ Sout,
                                                float* __restrict__ cout) {
    __shared__ float S[128 * 64];  // 32 KB
    int tid = threadIdx.x;
    int b = blockIdx.x;
    for (int i = tid; i < 128 * 16; i += 256) ((float4*)S)[i] = ((const float4*)Sin)[i];
    __syncthreads();
    if (b < 32) {
        int rr = tid >> 6;
        int c = tid & 63;
        int r = b * 4 + rr;
        const float* wrow = &Wl[r * 128];
        float s = 0.f;
#pragma unroll 8
        for (int k = 0; k < 128; ++k) s += wrow[k] * S[k * 64 + c];
        Sout[r * 64 + c] = s;
    } else if (tid < 64) {
        float s = 0.f;
        for (int k = 0; k < 128; ++k) s += bl[k] * S[k * 64 + tid];
        cout[tid] = s;
    }
}

// Transpose S0 (fp32 [128][64]) -> bf16 [n][c16] u4v, XOR-swizzled; also c4 = b4.
__global__ __launch_bounds__(256) void prep_z(const float* __restrict__ S0,
                                              const float* __restrict__ b4,
                                              u4v* __restrict__ Wt,
                                              float* __restrict__ c_all) {
    int idx = blockIdx.x * 256 + threadIdx.x;  // n*16 + c16, 1024 total
    if (blockIdx.x == 0 && threadIdx.x < 64) c_all[4 * 64 + threadIdx.x] = b4[threadIdx.x];
    if (idx >= 64 * 16) return;
    int n = idx >> 4, c16 = idx & 15;
    u4v o;
#pragma unroll
    for (int q = 0; q < 4; ++q)
        o[q] = bf16pack(S0[(size_t)(c16 * 8 + 2 * q) * 64 + n],
                        S0[(size_t)(c16 * 8 + 2 * q + 1) * 64 + n]);
    Wt[n * 16 + (c16 ^ (n & 7))] = o;
}

// ---------- degree polynomial (exact fp32, integer-valued) ----------

__global__ void deg_init(const int* __restrict__ row_ptr, float* __restrict__ d1) {
    int v = blockIdx.x * 256 + threadIdx.x;
    if (v < N_NODES) d1[v] = (float)(row_ptr[v + 1] - row_ptr[v]) + 1.0f;
}

// dn[v] = d[v] + sum_{u in in(v)} d[u]   (d is 400KB -> L2-resident gathers)
__global__ __launch_bounds__(256) void agg_scalar(const float* __restrict__ d,
                                                  const int* __restrict__ row_ptr,
                                                  const int* __restrict__ esrc,
                                                  float* __restrict__ dn) {
    int v = blockIdx.x * 256 + threadIdx.x;
    if (v >= N_NODES) return;
    int beg = row_ptr[v], end = row_ptr[v + 1];
    float s = d[v];
    for (int i = beg; i < end; ++i) s += d[esrc[i]];
    dn[v] = s;
}

// ---------- 64-dim aggregation passes (streaming, 2 edges/wave-instr) ----------
// zn[v] = z[v] + sum_{u in in(v)} z[u]   (bf16 -> bf16)

__global__ __launch_bounds__(256) void agg64_step(const uint* __restrict__ z,
                                                  const int* __restrict__ row_ptr,
                                                  const int* __restrict__ esrc,
                                                  uint* __restrict__ zn) {
    int lane = threadIdx.x & 63;
    int l32 = lane & 31;
    int half = lane >> 5;
    int wid = (blockIdx.x * blockDim.x + threadIdx.x) >> 6;
    int nw = (gridDim.x * blockDim.x) >> 6;
    for (int v = wid; v < N_NODES; v += nw) {
        f2v a = {0.f, 0.f};
        int beg = row_ptr[v], end = row_ptr[v + 1];
        int i = beg;
        for (; i + 16 <= end; i += 16) {
            uint k[8], u[8];
#pragma unroll
            for (int j = 0; j < 8; ++j) k[j] = (uint)esrc[i + 2 * j + half];
#pragma unroll
            for (int j = 0; j < 8; ++j) u[j] = z[k[j] * 32u + (uint)l32];
#pragma unroll
            for (int j = 0; j < 8; ++j) {
                f2v t = {bf_lo(u[j]), bf_hi(u[j])};
                a += t;
            }
        }
        for (; i < end; i += 2) {
            int idx = i + half;
            uint uu = 0u;
            if (idx < end) uu = z[(uint)esrc[idx] * 32u + (uint)l32];
            f2v t = {bf_lo(uu), bf_hi(uu)};
            a += t;
        }
        a.x += __shfl_xor(a.x, 32);
        a.y += __shfl_xor(a.y, 32);
        if (half == 0) {
            uint self = z[(uint)v * 32u + (uint)l32];
            __builtin_nontemporal_store(bf16pack(a.x + bf_lo(self), a.y + bf_hi(self)),
                                        &zn[(uint)v * 32u + (uint)l32]);
        }
    }
}

// Final pass: out[v] = z4[v] + sum_u z4[u]
//                    + d4[v]*c0 + d3[v]*c1 + d2[v]*c2 + (deg+1)*c3 + c4   (fp32)
__global__ __launch_bounds__(256) void agg64_last(const uint* __restrict__ z,
                                                  const int* __restrict__ row_ptr,
                                                  const int* __restrict__ esrc,
                                                  const float* __restrict__ d2,
                                                  const float* __restrict__ d3,
                                                  const float* __restrict__ d4,
                                                  const float* __restrict__ c_all,
                                                  float* __restrict__ out) {
    int lane = threadIdx.x & 63;
    int l32 = lane & 31;
    int half = lane >> 5;
    int wid = (blockIdx.x * blockDim.x + threadIdx.x) >> 6;
    int nw = (gridDim.x * blockDim.x) >> 6;
    f2v c0v = ((const f2v*)(c_all + 0))[l32];
    f2v c1v = ((const f2v*)(c_all + 64))[l32];
    f2v c2v = ((const f2v*)(c_all + 128))[l32];
    f2v c3v = ((const f2v*)(c_all + 192))[l32];
    f2v c4v = ((const f2v*)(c_all + 256))[l32];
    for (int v = wid; v < N_NODES; v += nw) {
        f2v a = {0.f, 0.f};
        int beg = row_ptr[v], end = row_ptr[v + 1];
        int i = beg;
        for (; i + 16 <= end; i += 16) {
            uint k[8], u[8];
#pragma unroll
            for (int j = 0; j < 8; ++j) k[j] = (uint)esrc[i + 2 * j + half];
#pragma unroll
            for (int j = 0; j < 8; ++j) u[j] = z[k[j] * 32u + (uint)l32];
#pragma unroll
            for (int j = 0; j < 8; ++j) {
                f2v t = {bf_lo(u[j]), bf_hi(u[j])};
                a += t;
            }
        }
        for (; i < end; i += 2) {
            int idx = i + half;
            uint uu = 0u;
            if (idx < end) uu = z[(uint)esrc[idx] * 32u + (uint)l32];
            f2v t = {bf_lo(uu), bf_hi(uu)};
            a += t;
        }
        a.x += __shfl_xor(a.x, 32);
        a.y += __shfl_xor(a.y, 32);
        if (half == 0) {
            uint self = z[(uint)v * 32u + (uint)l32];
            float w4 = d4[v], w3 = d3[v], w2 = d2[v];
            float w1 = (float)(end - beg) + 1.0f;
            f2v o;
            o.x = a.x + bf_lo(self) + w4 * c0v.x + w3 * c1v.x + w2 * c2v.x + w1 * c3v.x + c4v.x;
            o.y = a.y + bf_hi(self) + w4 * c0v.y + w3 * c1v.y + w2 * c2v.y + w1 * c3v.y + c4v.y;
            __builtin_nontemporal_store(o, &((f2v*)out)[(uint)v * 32u + (uint)l32]);
        }
    }
}

// ---------- MFMA GEMM: z0 = h (fp32 [N][128]) @ S0 -> bf16 [N][64] ----------

template <int NOUT, bool A_BF16>
__global__ __launch_bounds__(256) void mfma_gemm(const void* __restrict__ xv,
                                                 const u4v* __restrict__ Wt,
                                                 uint* __restrict__ y) {
    constexpr int STAGE = 32768 + NOUT * 256;
    constexpr int EPIL = 128 * NOUT * 4;
    constexpr int SMEM = STAGE > EPIL ? STAGE : EPIL;
    __shared__ char raw[SMEM];
    u4v* Asm = (u4v*)raw;                  // [128][16] swizzled
    u4v* Bsm = (u4v*)(raw + 32768);        // [NOUT][16] swizzled
    float* Cst = (float*)raw;              // [128][NOUT] epilogue overlay
    int tid = threadIdx.x;
    int m0 = blockIdx.x * 128;

    if constexpr (A_BF16) {
        const u4v* xp = (const u4v*)xv;
#pragma unroll
        for (int i = 0; i < 8; ++i) {
            int idx = tid + i * 256;
            int r = idx >> 4, c16 = idx & 15;
            int m = m0 + r;
            if (m >= N_NODES) m = N_NODES - 1;
            Asm[r * 16 + (c16 ^ (r & 7))] = xp[(size_t)m * 16 + c16];
        }
    } else {
        const float* x = (const float*)xv;
#pragma unroll
        for (int i = 0; i < 8; ++i) {
            int idx = tid + i * 256;
            int r = idx >> 4, c16 = idx & 15;
            int m = m0 + r;
            if (m >= N_NODES) m = N_NODES - 1;
            const float* src = &x[(size_t)m * 128 + c16 * 8];
            float4 v0 = *(const float4*)src;
            float4 v1 = *(const float4*)(src + 4);
            u4v o = {bf16pack(v0.x, v0.y), bf16pack(v0.z, v0.w),
                     bf16pack(v1.x, v1.y), bf16pack(v1.z, v1.w)};
            Asm[r * 16 + (c16 ^ (r & 7))] = o;
        }
    }
#pragma unroll
    for (int i = 0; i < NOUT * 16 / 256; ++i) Bsm[tid + i * 256] = Wt[tid + i * 256];
    __syncthreads();

    constexpr int NF = NOUT / 64;
    int lane = tid & 63;
    int w = tid >> 6;
    int n0w = w * (NOUT / 4);
    int lhi = lane >> 4, llo = lane & 15;
    f32x4 acc[8][NF];
#pragma unroll
    for (int i = 0; i < 8; ++i)
#pragma unroll
        for (int j = 0; j < NF; ++j) acc[i][j] = (f32x4){0.f, 0.f, 0.f, 0.f};

#pragma unroll
    for (int ks = 0; ks < 4; ++ks) {
        int cb = ks * 4 + lhi;
        s8v bfr[NF];
#pragma unroll
        for (int j = 0; j < NF; ++j) {
            int col = n0w + j * 16 + llo;
            u4v t = Bsm[col * 16 + (cb ^ (col & 7))];
            bfr[j] = *(s8v*)&t;
        }
#pragma unroll
        for (int i = 0; i < 8; ++i) {
            int row = i * 16 + llo;
            u4v t = Asm[row * 16 + (cb ^ (row & 7))];
            s8v a = *(s8v*)&t;
#pragma unroll
            for (int j = 0; j < NF; ++j)
                acc[i][j] = __builtin_amdgcn_mfma_f32_16x16x32_bf16(a, bfr[j], acc[i][j], 0, 0, 0);
        }
    }
    __syncthreads();
#pragma unroll
    for (int i = 0; i < 8; ++i)
#pragma unroll
        for (int j = 0; j < NF; ++j)
#pragma unroll
            for (int r = 0; r < 4; ++r)
                Cst[(i * 16 + lhi * 4 + r) * NOUT + n0w + j * 16 + llo] = acc[i][j][r];
    __syncthreads();
#pragma unroll
    for (int i = 0; i < 128 * NOUT / 2 / 256; ++i) {
        int idx = tid + i * 256;
        int m = idx / (NOUT / 2), np = idx % (NOUT / 2);
        if (m0 + m < N_NODES)
            y[(size_t)(m0 + m) * (NOUT / 2) + np] =
                bf16pack(Cst[m * NOUT + 2 * np], Cst[m * NOUT + 2 * np + 1]);
    }
}

extern "C" void kernel_launch(void* const* d_in, const int* in_sizes, int n_in,
                              void* d_out, int out_size, void* d_ws, size_t ws_size,
                              hipStream_t stream) {
    const float* h_in = (const float*)d_in[0];
    const void* edges = d_in[1];
    const float* W[5] = {(const float*)d_in[2], (const float*)d_in[4], (const float*)d_in[6],
                         (const float*)d_in[8], (const float*)d_in[10]};
    const float* B[5] = {(const float*)d_in[3], (const float*)d_in[5], (const float*)d_in[7],
                         (const float*)d_in[9], (const float*)d_in[11]};

    size_t off = 0;
    auto alloc = [&](size_t bytes) {
        void* p = (char*)d_ws + off;
        off = (off + bytes + 255) & ~(size_t)255;
        return p;
    };
    int* esorted = (int*)alloc((size_t)N_EDGES * 4);            // 12.8 MB
    int* row_ptr = (int*)alloc((size_t)(N_NODES + 1) * 4);
    int* hist2 = (int*)alloc((size_t)NCHUNKS * NB * 4);
    int* base2 = (int*)alloc((size_t)NCHUNKS * NB * 4);
    int* bcount = (int*)alloc((size_t)NB * 4);
    int* boff = (int*)alloc((size_t)(NB + 1) * 4);
    int* flag = (int*)alloc(256);
    float* Sa = (float*)alloc(128 * 64 * 4);                    // 32 KB ping
    float* Sb = (float*)alloc(128 * 64 * 4);                    // 32 KB pong
    float* c_all = (float*)alloc(5 * 64 * 4);
    u4v* Wt_z = (u4v*)alloc((size_t)64 * 16 * 16);              // 16 KB
    float* d1 = (float*)alloc((size_t)N_NODES * 4);
    float* d2 = (float*)alloc((size_t)N_NODES * 4);
    float* d3 = (float*)alloc((size_t)N_NODES * 4);
    float* d4 = (float*)alloc((size_t)N_NODES * 4);
    uint* zA = (uint*)alloc((size_t)N_NODES * 32 * 4);          // 12.8 MB
    uint* zB = (uint*)alloc((size_t)N_NODES * 32 * 4);          // 12.8 MB
    uint* tmp = (uint*)alloc((size_t)N_EDGES * 4);              // 12.8 MB (build only)

    // ---- build CSR ----
    detect_fmt<<<1, 64, 0, stream>>>((const uint*)edges, flag, row_ptr);
    hipMemsetAsync(bcount, 0, (size_t)NB * 4, stream);
    part_hist<<<NCHUNKS, 256, 0, stream>>>(edges, flag, hist2, bcount);
    scan_kernel<<<1, 1024, 0, stream>>>(bcount, boff, NB);
    chunk_scan<<<NB, 256, 0, stream>>>(hist2, boff, base2);
    part_scatter<<<NCHUNKS, 256, 0, stream>>>(edges, flag, base2, tmp);
    bucket_finalize<<<NB, 256, 0, stream>>>(tmp, boff, row_ptr, esorted);

    // ---- collapse prep: S_l = W_l..W_4 (parallel stages), c_l = b_l^T S_{l+1} ----
    matstage<<<33, 256, 0, stream>>>(W[3], B[3], W[4], Sa, c_all + 3 * 64);  // S3, c3
    matstage<<<33, 256, 0, stream>>>(W[2], B[2], Sa, Sb, c_all + 2 * 64);    // S2, c2
    matstage<<<33, 256, 0, stream>>>(W[1], B[1], Sb, Sa, c_all + 1 * 64);    // S1, c1
    matstage<<<33, 256, 0, stream>>>(W[0], B[0], Sa, Sb, c_all + 0 * 64);    // S0, c0
    prep_z<<<4, 256, 0, stream>>>(Sb, B[4], Wt_z, c_all);                    // Wt_z, c4

    // ---- degree polynomial d_k = (I+A)^k 1 (exact) ----
    deg_init<<<(N_NODES + 255) / 256, 256, 0, stream>>>(row_ptr, d1);
    agg_scalar<<<(N_NODES + 255) / 256, 256, 0, stream>>>(d1, row_ptr, esorted, d2);
    agg_scalar<<<(N_NODES + 255) / 256, 256, 0, stream>>>(d2, row_ptr, esorted, d3);
    agg_scalar<<<(N_NODES + 255) / 256, 256, 0, stream>>>(d3, row_ptr, esorted, d4);

    // ---- z0 = h @ S0; z_{k+1} = z_k + A z_k (x4); final pass + bias poly ----
    mfma_gemm<64, false><<<(N_NODES + 127) / 128, 256, 0, stream>>>(h_in, Wt_z, zA);
    agg64_step<<<2048, 256, 0, stream>>>(zA, row_ptr, esorted, zB);  // z1
    agg64_step<<<2048, 256, 0, stream>>>(zB, row_ptr, esorted, zA);  // z2
    agg64_step<<<2048, 256, 0, stream>>>(zA, row_ptr, esorted, zB);  // z3
    agg64_step<<<2048, 256, 0, stream>>>(zB, row_ptr, esorted, zA);  // z4
    agg64_last<<<2048, 256, 0, stream>>>(zA, row_ptr, esorted, d2, d3, d4, c_all,
                                         (float*)d_out);
}